// Round 2
// baseline (801.826 us; speedup 1.0000x reference)
//
#include <hip/hip_runtime.h>
#include <hip/hip_bf16.h>

#define IN_F   4096
#define OUT_F  11008
#define NHIGH  2752
#define NLOW   8256
#define M_TOT  4096   // B*S = 2*2048

typedef __attribute__((ext_vector_type(8))) short bf16x8;
typedef __attribute__((ext_vector_type(4))) float f32x4;

__device__ __forceinline__ short f2bf(float f) {
    union { float f; unsigned u; } v; v.f = f;
    unsigned r = (v.u + 0x7fffu + ((v.u >> 16) & 1u)) >> 16;
    return (short)(r & 0xffffu);
}

__device__ __forceinline__ void async16(const void* g, const void* l) {
    __builtin_amdgcn_global_load_lds(
        (const __attribute__((address_space(1))) unsigned int*)g,
        (__attribute__((address_space(3))) unsigned int*)l, 16, 0, 0);
}

// ---------------- kernel 1: x f32 -> bf16 ----------------
__global__ void cvt_x_kernel(const float* __restrict__ x, short* __restrict__ xb) {
    const int nv = (M_TOT * IN_F) / 8;
    for (int i = blockIdx.x * blockDim.x + threadIdx.x; i < nv;
         i += gridDim.x * blockDim.x) {
        const float4* p = (const float4*)(x + (long)i * 8);
        float4 a = p[0], b = p[1];
        bf16x8 o;
        o[0] = f2bf(a.x); o[1] = f2bf(a.y); o[2] = f2bf(a.z); o[3] = f2bf(a.w);
        o[4] = f2bf(b.x); o[5] = f2bf(b.y); o[6] = f2bf(b.z); o[7] = f2bf(b.w);
        *(bf16x8*)(xb + (long)i * 8) = o;
    }
}

// ---------------- kernel 2: dequant + permute + transpose -> W_t[n][k] bf16 ----------------
// grid (172, 64): blockIdx.x = n-tile (64 cols), blockIdx.y = k-tile (64 rows). 256 thr.
__global__ void dequant_kernel(const int* __restrict__ hw, const float* __restrict__ hs,
                               const int* __restrict__ lw, const float* __restrict__ s1,
                               const float* __restrict__ s2, const float* __restrict__ zp,
                               const int* __restrict__ cinv,
                               short* __restrict__ wt) {
    __shared__ short tile[64 * 66];   // [n_local][k_local], stride 66 to dodge bank conflicts
    const int t  = threadIdx.x;
    const int n0 = blockIdx.x * 64;
    const int k0 = blockIdx.y * 64;
    const int nl = t & 63;   // lane -> n_local
    const int w  = t >> 6;   // wave -> k_local base (wave-uniform k)

    const int c = cinv[n0 + nl];
    if (c < NHIGH) {
        const int ci = c;
        #pragma unroll
        for (int i = 0; i < 16; ++i) {
            const int kl = w + 4 * i;
            const int k  = k0 + kl;
            float val = (float)hw[(long)k * NHIGH + ci] * hs[(k >> 7) * NHIGH + ci];
            tile[nl * 66 + kl] = f2bf(val);
        }
    } else {
        const int ci = c - NHIGH;
        const float s2v = s2[ci];
        #pragma unroll
        for (int i = 0; i < 16; ++i) {
            const int kl = w + 4 * i;
            const int k  = k0 + kl;
            float val = ((float)lw[(long)k * NLOW + ci] - zp[k]) * s1[k] * s2v;
            tile[nl * 66 + kl] = f2bf(val);
        }
    }
    __syncthreads();
    // write out: thread t -> row n0 + t/4, k chunk (t%4)*16 (32B, 16B-aligned)
    const int on = t >> 2;
    const int kq = (t & 3) * 16;
    bf16x8 o0, o1;
    #pragma unroll
    for (int j = 0; j < 8; ++j) {
        o0[j] = tile[on * 66 + kq + j];
        o1[j] = tile[on * 66 + kq + 8 + j];
    }
    short* dst = wt + (long)(n0 + on) * IN_F + k0 + kq;
    *(bf16x8*)dst       = o0;
    *(bf16x8*)(dst + 8) = o1;
}

// ---------------- kernel 3: GEMM C[m][n] = A[m][k] * Wt[n][k]^T + bias ----------------
#define BM 128
#define BN 128
#define BK 64
#define KT (IN_F / BK)

__global__ __launch_bounds__(256, 2) void gemm_kernel(
    const short* __restrict__ A,    // [M_TOT][IN_F] bf16
    const short* __restrict__ Bt,   // [OUT_F][IN_F] bf16
    const float* __restrict__ bias, // [OUT_F]
    float* __restrict__ C) {        // [M_TOT][OUT_F]
    __shared__ __align__(16) short As[BM * BK];
    __shared__ __align__(16) short Bs[BN * BK];

    const int t    = threadIdx.x;
    const int lane = t & 63;
    const int w    = t >> 6;        // 0..3
    const int wr   = w >> 1, wc = w & 1;
    const int m0   = blockIdx.y * BM;
    const int n0   = blockIdx.x * BN;

    // staging geometry: per call j, wave w covers LDS bytes [(w*4+j)*1024, +1024)
    // lane l -> tile row (w*4+j)*8 + l/8, col element (l%8)*8 (16B)
    const int srow = (w * 4) * 8 + (lane >> 3);
    const int scol = (lane & 7) * 8;
    const short* gA = A  + (long)(m0 + srow) * IN_F + scol;
    const short* gB = Bt + (long)(n0 + srow) * IN_F + scol;

    f32x4 acc[4][4];
    #pragma unroll
    for (int mi = 0; mi < 4; ++mi)
        #pragma unroll
        for (int ni = 0; ni < 4; ++ni)
            acc[mi][ni] = (f32x4){0.f, 0.f, 0.f, 0.f};

    for (int kt = 0; kt < KT; ++kt) {
        const int kofs = kt * BK;
        #pragma unroll
        for (int j = 0; j < 4; ++j) {
            async16(gA + kofs + j * 8 * IN_F, (char*)As + (w * 4 + j) * 1024);
            async16(gB + kofs + j * 8 * IN_F, (char*)Bs + (w * 4 + j) * 1024);
        }
        __syncthreads();   // drains vmcnt before barrier (compiler-emitted)
        #pragma unroll
        for (int kk = 0; kk < 2; ++kk) {
            bf16x8 af[4], bfr[4];
            #pragma unroll
            for (int mi = 0; mi < 4; ++mi)
                af[mi] = *(const bf16x8*)(As + (wr * 64 + mi * 16 + (lane & 15)) * BK
                                             + kk * 32 + (lane >> 4) * 8);
            #pragma unroll
            for (int ni = 0; ni < 4; ++ni)
                bfr[ni] = *(const bf16x8*)(Bs + (wc * 64 + ni * 16 + (lane & 15)) * BK
                                              + kk * 32 + (lane >> 4) * 8);
            #pragma unroll
            for (int mi = 0; mi < 4; ++mi)
                #pragma unroll
                for (int ni = 0; ni < 4; ++ni)
                    acc[mi][ni] = __builtin_amdgcn_mfma_f32_16x16x32_bf16(
                        af[mi], bfr[ni], acc[mi][ni], 0, 0, 0);
        }
        __syncthreads();
    }

    // epilogue: C/D layout col = lane&15, row = (lane>>4)*4 + r
    const int crow  = m0 + wr * 64 + (lane >> 4) * 4;
    const int ccol0 = n0 + wc * 64 + (lane & 15);
    #pragma unroll
    for (int ni = 0; ni < 4; ++ni) {
        const float bv = bias[ccol0 + ni * 16];
        #pragma unroll
        for (int mi = 0; mi < 4; ++mi) {
            #pragma unroll
            for (int r = 0; r < 4; ++r) {
                C[(long)(crow + mi * 16 + r) * OUT_F + ccol0 + ni * 16] =
                    acc[mi][ni][r] + bv;
            }
        }
    }
}

extern "C" void kernel_launch(void* const* d_in, const int* in_sizes, int n_in,
                              void* d_out, int out_size, void* d_ws, size_t ws_size,
                              hipStream_t stream) {
    const float* x    = (const float*)d_in[0];
    const int*   hw   = (const int*)d_in[1];
    const float* hs   = (const float*)d_in[2];
    const int*   lw   = (const int*)d_in[3];
    const float* s1   = (const float*)d_in[4];
    const float* s2   = (const float*)d_in[5];
    const float* zp   = (const float*)d_in[6];
    const int*   cinv = (const int*)d_in[7];
    const float* bias = (const float*)d_in[8];
    float*       out  = (float*)d_out;

    short* wt = (short*)d_ws;                                    // 90,177,536 B
    short* xb = (short*)((char*)d_ws + (size_t)OUT_F * IN_F * 2); // +33,554,432 B

    cvt_x_kernel<<<2048, 256, 0, stream>>>(x, xb);
    dequant_kernel<<<dim3(OUT_F / 64, IN_F / 64), 256, 0, stream>>>(
        hw, hs, lw, s1, s2, zp, cinv, wt);
    gemm_kernel<<<dim3(OUT_F / BN, M_TOT / BM), 256, 0, stream>>>(xb, wt, bias, out);
}

// Round 3
// 482.162 us; speedup vs baseline: 1.6630x; 1.6630x over previous
//
#include <hip/hip_runtime.h>
#include <hip/hip_bf16.h>

#define IN_F   4096
#define OUT_F  11008
#define NHIGH  2752
#define NLOW   8256
#define M_TOT  4096   // B*S = 2*2048

typedef __attribute__((ext_vector_type(8))) short bf16x8;
typedef __attribute__((ext_vector_type(4))) float f32x4;

__device__ __forceinline__ short f2bf(float f) {
    union { float f; unsigned u; } v; v.f = f;
    unsigned r = (v.u + 0x7fffu + ((v.u >> 16) & 1u)) >> 16;
    return (short)(r & 0xffffu);
}

__device__ __forceinline__ void async16(const void* g, const void* l) {
    __builtin_amdgcn_global_load_lds(
        (const __attribute__((address_space(1))) unsigned int*)g,
        (__attribute__((address_space(3))) unsigned int*)l, 16, 0, 0);
}

// ---------------- kernel 0: forward permutation fwd[cinv[n]] = n ----------------
__global__ void fwd_perm_kernel(const int* __restrict__ cinv, int* __restrict__ fwd) {
    int n = blockIdx.x * blockDim.x + threadIdx.x;
    if (n < OUT_F) fwd[cinv[n]] = n;
}

// ---------------- kernel 1: x f32 -> bf16 ----------------
__global__ void cvt_x_kernel(const float* __restrict__ x, short* __restrict__ xb) {
    const int nv = (M_TOT * IN_F) / 8;
    for (int i = blockIdx.x * blockDim.x + threadIdx.x; i < nv;
         i += gridDim.x * blockDim.x) {
        const float4* p = (const float4*)(x + (long)i * 8);
        float4 a = p[0], b = p[1];
        bf16x8 o;
        o[0] = f2bf(a.x); o[1] = f2bf(a.y); o[2] = f2bf(a.z); o[3] = f2bf(a.w);
        o[4] = f2bf(b.x); o[5] = f2bf(b.y); o[6] = f2bf(b.z); o[7] = f2bf(b.w);
        *(bf16x8*)(xb + (long)i * 8) = o;
    }
}

// ---------------- kernel 2: dequant (source-major, coalesced) + scatter-permute ----------------
// grid (172, 64): blockIdx.x = SOURCE col tile (64 cols; <43 high, else low),
// blockIdx.y = k-tile (64 rows). 256 thr. Reads coalesced; writes to wt[fwd[c]][k].
__global__ void dequant_kernel(const int* __restrict__ hw, const float* __restrict__ hs,
                               const int* __restrict__ lw, const float* __restrict__ s1,
                               const float* __restrict__ s2, const float* __restrict__ zp,
                               const int* __restrict__ fwd,
                               short* __restrict__ wt) {
    __shared__ short tile[64 * 66];   // [src_col_local][k_local], stride 66
    const int t  = threadIdx.x;
    const int c0 = blockIdx.x * 64;   // source column base (concat space)
    const int k0 = blockIdx.y * 64;
    const int cl = t & 63;            // lane -> source col local
    const int w  = t >> 6;            // wave -> k_local base

    if (c0 < NHIGH) {
        const int ci = c0 + cl;       // column in hw
        #pragma unroll
        for (int i = 0; i < 16; ++i) {
            const int kl = w + 4 * i;
            const int k  = k0 + kl;
            // coalesced: 64 lanes read 64 consecutive int32
            float val = (float)hw[(long)k * NHIGH + ci] * hs[(k >> 7) * NHIGH + ci];
            tile[cl * 66 + kl] = f2bf(val);
        }
    } else {
        const int ci = c0 - NHIGH + cl;  // column in lw
        const float s2v = s2[ci];
        #pragma unroll
        for (int i = 0; i < 16; ++i) {
            const int kl = w + 4 * i;
            const int k  = k0 + kl;
            float val = ((float)lw[(long)k * NLOW + ci] - zp[k]) * s1[k] * s2v;
            tile[cl * 66 + kl] = f2bf(val);
        }
    }
    __syncthreads();
    // write out: thread t -> source col c0 + t/4 -> dest row fwd[c], k chunk (t%4)*16
    const int oc = t >> 2;
    const int kq = (t & 3) * 16;
    bf16x8 o0, o1;
    #pragma unroll
    for (int j = 0; j < 8; ++j) {
        o0[j] = tile[oc * 66 + kq + j];
        o1[j] = tile[oc * 66 + kq + 8 + j];
    }
    const int ndst = fwd[c0 + oc];
    short* dst = wt + (long)ndst * IN_F + k0 + kq;
    *(bf16x8*)dst       = o0;
    *(bf16x8*)(dst + 8) = o1;
}

// ---------------- kernel 3: GEMM C[m][n] = A[m][k] * Wt[n][k]^T + bias ----------------
#define BM 128
#define BN 128
#define BK 64
#define KT (IN_F / BK)
#define NTILES (OUT_F / BN)   // 86
#define MTILES (M_TOT / BM)   // 32
#define NWG (NTILES * MTILES) // 2752, divisible by 8
#define GSUP 8                // m-panels per super-row

__global__ __launch_bounds__(256, 2) void gemm_kernel(
    const short* __restrict__ A,    // [M_TOT][IN_F] bf16
    const short* __restrict__ Bt,   // [OUT_F][IN_F] bf16
    const float* __restrict__ bias, // [OUT_F]
    float* __restrict__ C) {        // [M_TOT][OUT_F]
    __shared__ __align__(16) short As[BM * BK];
    __shared__ __align__(16) short Bs[BN * BK];

    const int t    = threadIdx.x;
    const int lane = t & 63;
    const int w    = t >> 6;        // 0..3
    const int wr   = w >> 1, wc = w & 1;

    // XCD-aware swizzle (bijective: NWG % 8 == 0), then supertile raster:
    // super-row = GSUP m-panels; within super-row, m fastest (B-panel reused GSUP×).
    const int swz   = (blockIdx.x % 8) * (NWG / 8) + blockIdx.x / 8;
    const int sr    = swz / (GSUP * NTILES);
    const int in_sr = swz % (GSUP * NTILES);
    const int nb    = in_sr / GSUP;
    const int mb    = sr * GSUP + (in_sr % GSUP);
    const int m0    = mb * BM;
    const int n0    = nb * BN;

    // staging geometry: per call j, wave w covers LDS bytes [(w*4+j)*1024, +1024)
    const int srow = (w * 4) * 8 + (lane >> 3);
    const int scol = (lane & 7) * 8;
    const short* gA = A  + (long)(m0 + srow) * IN_F + scol;
    const short* gB = Bt + (long)(n0 + srow) * IN_F + scol;

    f32x4 acc[4][4];
    #pragma unroll
    for (int mi = 0; mi < 4; ++mi)
        #pragma unroll
        for (int ni = 0; ni < 4; ++ni)
            acc[mi][ni] = (f32x4){0.f, 0.f, 0.f, 0.f};

    for (int kt = 0; kt < KT; ++kt) {
        const int kofs = kt * BK;
        #pragma unroll
        for (int j = 0; j < 4; ++j) {
            async16(gA + kofs + j * 8 * IN_F, (char*)As + (w * 4 + j) * 1024);
            async16(gB + kofs + j * 8 * IN_F, (char*)Bs + (w * 4 + j) * 1024);
        }
        __syncthreads();
        #pragma unroll
        for (int kk = 0; kk < 2; ++kk) {
            bf16x8 af[4], bfr[4];
            #pragma unroll
            for (int mi = 0; mi < 4; ++mi)
                af[mi] = *(const bf16x8*)(As + (wr * 64 + mi * 16 + (lane & 15)) * BK
                                             + kk * 32 + (lane >> 4) * 8);
            #pragma unroll
            for (int ni = 0; ni < 4; ++ni)
                bfr[ni] = *(const bf16x8*)(Bs + (wc * 64 + ni * 16 + (lane & 15)) * BK
                                              + kk * 32 + (lane >> 4) * 8);
            #pragma unroll
            for (int mi = 0; mi < 4; ++mi)
                #pragma unroll
                for (int ni = 0; ni < 4; ++ni)
                    acc[mi][ni] = __builtin_amdgcn_mfma_f32_16x16x32_bf16(
                        af[mi], bfr[ni], acc[mi][ni], 0, 0, 0);
        }
        __syncthreads();
    }

    // epilogue: C/D layout col = lane&15, row = (lane>>4)*4 + r
    const int crow  = m0 + wr * 64 + (lane >> 4) * 4;
    const int ccol0 = n0 + wc * 64 + (lane & 15);
    #pragma unroll
    for (int ni = 0; ni < 4; ++ni) {
        const float bv = bias[ccol0 + ni * 16];
        #pragma unroll
        for (int mi = 0; mi < 4; ++mi) {
            #pragma unroll
            for (int r = 0; r < 4; ++r) {
                C[(long)(crow + mi * 16 + r) * OUT_F + ccol0 + ni * 16] =
                    acc[mi][ni][r] + bv;
            }
        }
    }
}

extern "C" void kernel_launch(void* const* d_in, const int* in_sizes, int n_in,
                              void* d_out, int out_size, void* d_ws, size_t ws_size,
                              hipStream_t stream) {
    const float* x    = (const float*)d_in[0];
    const int*   hw   = (const int*)d_in[1];
    const float* hs   = (const float*)d_in[2];
    const int*   lw   = (const int*)d_in[3];
    const float* s1   = (const float*)d_in[4];
    const float* s2   = (const float*)d_in[5];
    const float* zp   = (const float*)d_in[6];
    const int*   cinv = (const int*)d_in[7];
    const float* bias = (const float*)d_in[8];
    float*       out  = (float*)d_out;

    short* wt  = (short*)d_ws;                                     // 90,177,536 B
    short* xb  = (short*)((char*)d_ws + (size_t)OUT_F * IN_F * 2); // +33,554,432 B
    int*   fwd = (int*)((char*)d_ws + (size_t)OUT_F * IN_F * 2
                                    + (size_t)M_TOT * IN_F * 2);   // +44,032 B

    fwd_perm_kernel<<<(OUT_F + 255) / 256, 256, 0, stream>>>(cinv, fwd);
    cvt_x_kernel<<<2048, 256, 0, stream>>>(x, xb);
    dequant_kernel<<<dim3(OUT_F / 64, IN_F / 64), 256, 0, stream>>>(
        hw, hs, lw, s1, s2, zp, fwd, wt);
    gemm_kernel<<<NWG, 256, 0, stream>>>(xb, wt, bias, out);
}

// Round 4
// 412.007 us; speedup vs baseline: 1.9461x; 1.1703x over previous
//
#include <hip/hip_runtime.h>
#include <hip/hip_bf16.h>

#define IN_F   4096
#define OUT_F  11008
#define NHIGH  2752
#define NLOW   8256
#define M_TOT  4096   // B*S = 2*2048

typedef __attribute__((ext_vector_type(8))) short bf16x8;
typedef __attribute__((ext_vector_type(4))) float f32x4;

__device__ __forceinline__ short f2bf(float f) {
    union { float f; unsigned u; } v; v.f = f;
    unsigned r = (v.u + 0x7fffu + ((v.u >> 16) & 1u)) >> 16;
    return (short)(r & 0xffffu);
}

__device__ __forceinline__ void async16(const void* g, const void* l) {
    __builtin_amdgcn_global_load_lds(
        (const __attribute__((address_space(1))) unsigned int*)g,
        (__attribute__((address_space(3))) unsigned int*)l, 16, 0, 0);
}

// ---------------- kernel 0: forward permutation fwd[cinv[n]] = n ----------------
__global__ void fwd_perm_kernel(const int* __restrict__ cinv, int* __restrict__ fwd) {
    int n = blockIdx.x * blockDim.x + threadIdx.x;
    if (n < OUT_F) fwd[cinv[n]] = n;
}

// ---------------- kernel 1: x f32 -> bf16 ----------------
__global__ void cvt_x_kernel(const float* __restrict__ x, short* __restrict__ xb) {
    const int nv = (M_TOT * IN_F) / 8;
    for (int i = blockIdx.x * blockDim.x + threadIdx.x; i < nv;
         i += gridDim.x * blockDim.x) {
        const float4* p = (const float4*)(x + (long)i * 8);
        float4 a = p[0], b = p[1];
        bf16x8 o;
        o[0] = f2bf(a.x); o[1] = f2bf(a.y); o[2] = f2bf(a.z); o[3] = f2bf(a.w);
        o[4] = f2bf(b.x); o[5] = f2bf(b.y); o[6] = f2bf(b.z); o[7] = f2bf(b.w);
        *(bf16x8*)(xb + (long)i * 8) = o;
    }
}

// ---------------- kernel 2: dequant (source-major, coalesced) + scatter-permute ----------------
__global__ void dequant_kernel(const int* __restrict__ hw, const float* __restrict__ hs,
                               const int* __restrict__ lw, const float* __restrict__ s1,
                               const float* __restrict__ s2, const float* __restrict__ zp,
                               const int* __restrict__ fwd,
                               short* __restrict__ wt) {
    __shared__ short tile[64 * 66];
    const int t  = threadIdx.x;
    const int c0 = blockIdx.x * 64;
    const int k0 = blockIdx.y * 64;
    const int cl = t & 63;
    const int w  = t >> 6;

    if (c0 < NHIGH) {
        const int ci = c0 + cl;
        #pragma unroll
        for (int i = 0; i < 16; ++i) {
            const int kl = w + 4 * i;
            const int k  = k0 + kl;
            float val = (float)hw[(long)k * NHIGH + ci] * hs[(k >> 7) * NHIGH + ci];
            tile[cl * 66 + kl] = f2bf(val);
        }
    } else {
        const int ci = c0 - NHIGH + cl;
        const float s2v = s2[ci];
        #pragma unroll
        for (int i = 0; i < 16; ++i) {
            const int kl = w + 4 * i;
            const int k  = k0 + kl;
            float val = ((float)lw[(long)k * NLOW + ci] - zp[k]) * s1[k] * s2v;
            tile[cl * 66 + kl] = f2bf(val);
        }
    }
    __syncthreads();
    const int oc = t >> 2;
    const int kq = (t & 3) * 16;
    bf16x8 o0, o1;
    #pragma unroll
    for (int j = 0; j < 8; ++j) {
        o0[j] = tile[oc * 66 + kq + j];
        o1[j] = tile[oc * 66 + kq + 8 + j];
    }
    const int ndst = fwd[c0 + oc];
    short* dst = wt + (long)ndst * IN_F + k0 + kq;
    *(bf16x8*)dst       = o0;
    *(bf16x8*)(dst + 8) = o1;
}

// ---------------- kernel 3: 256x256 8-phase GEMM ----------------
// C[m][n] = A[m][k] * Bt[n][k]^T + bias.  512 thr = 8 waves (2Mx4N), BK=64.
// LDS 128KB: buf{0,1} x (A 32KB | B 32KB), row stride 128B, XOR-swizzle
// S(r,cb)=cb^((r&7)<<4). Stage = linear dest + pre-swizzled global source.
#define BM 256
#define BN 256
#define BK 64
#define KT (IN_F / BK)        // 64
#define NTIL (OUT_F / BN)     // 43
#define MTIL (M_TOT / BM)     // 16
#define NWG2 (NTIL * MTIL)    // 688 (= 8 * 86)

#define BAR()    __builtin_amdgcn_s_barrier()
#define LGKM0()  asm volatile("s_waitcnt lgkmcnt(0)" ::: "memory")
#define VMC(N)   asm volatile("s_waitcnt vmcnt(" #N ")" ::: "memory")

__global__ __launch_bounds__(512, 2) void gemm_kernel(
    const short* __restrict__ A,    // [M_TOT][IN_F] bf16
    const short* __restrict__ Bt,   // [OUT_F][IN_F] bf16
    const float* __restrict__ bias,
    float* __restrict__ C) {
    __shared__ __align__(16) short lds_s[65536];   // 128 KiB
    char* const lds = (char*)lds_s;

    const int t    = threadIdx.x;
    const int lane = t & 63;
    const int w    = t >> 6;      // 0..7
    const int wr   = w >> 2;      // 0..1  (M)
    const int wc   = w & 3;       // 0..3  (N)

    // XCD-bijective swizzle + supertile raster (4 m-tiles per super-row)
    const int swz   = (blockIdx.x % 8) * (NWG2 / 8) + blockIdx.x / 8;
    const int sr    = swz / (4 * NTIL);
    const int in_sr = swz % (4 * NTIL);
    const int nb    = in_sr / 4;
    const int mb    = sr * 4 + (in_sr & 3);
    const int m0    = mb * BM;
    const int n0    = nb * BN;

    // staging: per wave w, round q, lane l -> half row q*64 + w*8 + (l>>3),
    // source col-byte pre-swizzled: ((l&7)^(l>>3))*16
    const int srow = w * 8 + (lane >> 3);
    const int scb  = ((lane & 7) ^ (lane >> 3)) * 16;
    const char* gA0 = (const char*)A  + (long)(m0 + srow) * (IN_F * 2) + scb;
    const char* gB0 = (const char*)Bt + (long)(n0 + srow) * (IN_F * 2) + scb;

    // ds_read lane bases: row=(lane&15), col-byte cb0=(lane>>4)*16, sw=(lane&7)<<4
    const int rl  = (lane & 15) * 128;
    const int kb0 = ((lane >> 4) * 16) ^ ((lane & 7) << 4);
    const int kb1 = kb0 ^ 64;

    // A region(buf)=buf*65536; B region=buf*65536+32768; half h at +h*16384,
    // stage round q at +q*8192, wave slice +w*1024.
#define STAGE(gbase, region_off, h, ktile) do {                                  \
        const char* _g = (gbase) + (long)((h) * 128) * (IN_F * 2) + (ktile) * 128; \
        char* _l = lds + (region_off) + (h) * 16384 + w * 1024;                  \
        async16(_g,                      _l);                                    \
        async16(_g + (long)64 * (IN_F * 2), _l + 8192);                          \
    } while (0)

    f32x4 acc[8][4];
    #pragma unroll
    for (int i = 0; i < 8; ++i)
        #pragma unroll
        for (int j = 0; j < 4; ++j)
            acc[i][j] = (f32x4){0.f, 0.f, 0.f, 0.f};

    bf16x8 a[4][2], b0[2][2], b1[2][2];

#define RD_A(buf, mq) do {                                                       \
        char* _p = lds + (buf) * 65536 + wr * 16384 + (mq) * 8192 + rl;          \
        _Pragma("unroll")                                                        \
        for (int _j = 0; _j < 4; ++_j) {                                         \
            a[_j][0] = *(const bf16x8*)(_p + _j * 2048 + kb0);                   \
            a[_j][1] = *(const bf16x8*)(_p + _j * 2048 + kb1);                   \
        }                                                                        \
    } while (0)

#define RD_B(buf, nq, breg) do {                                                 \
        char* _p = lds + (buf) * 65536 + 32768 + wc * 8192 + (nq) * 4096 + rl;   \
        _Pragma("unroll")                                                        \
        for (int _n = 0; _n < 2; ++_n) {                                         \
            breg[_n][0] = *(const bf16x8*)(_p + _n * 2048 + kb0);                \
            breg[_n][1] = *(const bf16x8*)(_p + _n * 2048 + kb1);                \
        }                                                                        \
    } while (0)

#define MMA_Q(mq, nq, breg) do {                                                 \
        __builtin_amdgcn_s_setprio(1);                                           \
        _Pragma("unroll")                                                        \
        for (int _j = 0; _j < 4; ++_j)                                           \
        _Pragma("unroll")                                                        \
        for (int _n = 0; _n < 2; ++_n) {                                         \
            acc[(mq)*4+_j][(nq)*2+_n] = __builtin_amdgcn_mfma_f32_16x16x32_bf16( \
                a[_j][0], breg[_n][0], acc[(mq)*4+_j][(nq)*2+_n], 0, 0, 0);      \
            acc[(mq)*4+_j][(nq)*2+_n] = __builtin_amdgcn_mfma_f32_16x16x32_bf16( \
                a[_j][1], breg[_n][1], acc[(mq)*4+_j][(nq)*2+_n], 0, 0, 0);      \
        }                                                                        \
        __builtin_amdgcn_s_setprio(0);                                           \
    } while (0)

    // prologue: buf0 = tile 0 (4 halves), buf1.A h0 = tile 1  (10 loads/thread)
    STAGE(gA0, 0,     0, 0);
    STAGE(gA0, 0,     1, 0);
    STAGE(gB0, 32768, 0, 0);
    STAGE(gB0, 32768, 1, 0);
    STAGE(gA0, 65536, 0, 1);
    VMC(2);
    BAR();

    #pragma unroll 1
    for (int it = 0; it < KT / 2; ++it) {
        const int kt1 = 2 * it + 1;
        const int kt2 = (2 * it + 2 < KT) ? 2 * it + 2 : KT - 1;  // dummy on last iter
        const int kt3 = (2 * it + 3 < KT) ? 2 * it + 3 : KT - 1;

        // ---- K-tile 2it (buf0) ----
        // ph1
        RD_A(0, 0); RD_B(0, 0, b0);
        STAGE(gA0, 65536 + 0,     1, kt1);   // buf1.A h1
        BAR(); LGKM0();
        MMA_Q(0, 0, b0);
        BAR();
        // ph2
        RD_B(0, 1, b1);
        STAGE(gB0, 65536 + 32768, 0, kt1);   // buf1.B h0
        BAR(); LGKM0();
        MMA_Q(0, 1, b1);
        BAR();
        // ph3
        RD_A(0, 1);
        STAGE(gB0, 65536 + 32768, 1, kt1);   // buf1.B h1
        BAR(); LGKM0();
        MMA_Q(1, 1, b1);
        BAR();
        // ph4
        STAGE(gA0, 0,             0, kt2);   // buf0.A h0 (tile 2it+2)
        BAR();
        MMA_Q(1, 0, b0);
        VMC(2);                               // tile 2it+1's 8 loads landed
        BAR();

        // ---- K-tile 2it+1 (buf1) ----
        // ph5
        RD_A(1, 0); RD_B(1, 0, b0);
        STAGE(gA0, 0,             1, kt2);   // buf0.A h1
        BAR(); LGKM0();
        MMA_Q(0, 0, b0);
        BAR();
        // ph6
        RD_B(1, 1, b1);
        STAGE(gB0, 32768,         0, kt2);   // buf0.B h0
        BAR(); LGKM0();
        MMA_Q(0, 1, b1);
        BAR();
        // ph7
        RD_A(1, 1);
        STAGE(gB0, 32768,         1, kt2);   // buf0.B h1
        BAR(); LGKM0();
        MMA_Q(1, 1, b1);
        BAR();
        // ph8
        STAGE(gA0, 65536,         0, kt3);   // buf1.A h0 (tile 2it+3)
        BAR();
        MMA_Q(1, 0, b0);
        VMC(2);                               // tile 2it+2's 8 loads landed
        BAR();
    }

    asm volatile("s_waitcnt vmcnt(0)" ::: "memory");  // drain dummy stages

    // epilogue: C/D col = lane&15, row = (lane>>4)*4 + r
    const int er = m0 + wr * 128 + (lane >> 4) * 4;
    const int ec = n0 + wc * 64 + (lane & 15);
    #pragma unroll
    for (int ni = 0; ni < 4; ++ni) {
        const float bv = bias[ec + ni * 16];
        #pragma unroll
        for (int mi = 0; mi < 8; ++mi) {
            #pragma unroll
            for (int r = 0; r < 4; ++r) {
                C[(long)(er + mi * 16 + r) * OUT_F + ec + ni * 16] =
                    acc[mi][ni][r] + bv;
            }
        }
    }
}

extern "C" void kernel_launch(void* const* d_in, const int* in_sizes, int n_in,
                              void* d_out, int out_size, void* d_ws, size_t ws_size,
                              hipStream_t stream) {
    const float* x    = (const float*)d_in[0];
    const int*   hw   = (const int*)d_in[1];
    const float* hs   = (const float*)d_in[2];
    const int*   lw   = (const int*)d_in[3];
    const float* s1   = (const float*)d_in[4];
    const float* s2   = (const float*)d_in[5];
    const float* zp   = (const float*)d_in[6];
    const int*   cinv = (const int*)d_in[7];
    const float* bias = (const float*)d_in[8];
    float*       out  = (float*)d_out;

    short* wt  = (short*)d_ws;                                     // 90,177,536 B
    short* xb  = (short*)((char*)d_ws + (size_t)OUT_F * IN_F * 2); // +33,554,432 B
    int*   fwd = (int*)((char*)d_ws + (size_t)OUT_F * IN_F * 2
                                    + (size_t)M_TOT * IN_F * 2);   // +44,032 B

    fwd_perm_kernel<<<(OUT_F + 255) / 256, 256, 0, stream>>>(cinv, fwd);
    cvt_x_kernel<<<2048, 256, 0, stream>>>(x, xb);
    dequant_kernel<<<dim3(OUT_F / 64, IN_F / 64), 256, 0, stream>>>(
        hw, hs, lw, s1, s2, zp, fwd, wt);
    gemm_kernel<<<NWG2, 512, 0, stream>>>(xb, wt, bias, out);
}

// Round 5
// 404.693 us; speedup vs baseline: 1.9813x; 1.0181x over previous
//
#include <hip/hip_runtime.h>
#include <hip/hip_bf16.h>

#define IN_F   4096
#define OUT_F  11008
#define NHIGH  2752
#define NLOW   8256
#define M_TOT  4096   // B*S = 2*2048

typedef __attribute__((ext_vector_type(8))) short bf16x8;
typedef __attribute__((ext_vector_type(4))) float f32x4;
typedef __attribute__((ext_vector_type(4))) float f32x4v;

__device__ __forceinline__ short f2bf(float f) {
    union { float f; unsigned u; } v; v.f = f;
    unsigned r = (v.u + 0x7fffu + ((v.u >> 16) & 1u)) >> 16;
    return (short)(r & 0xffffu);
}

__device__ __forceinline__ void async16(const void* g, const void* l) {
    __builtin_amdgcn_global_load_lds(
        (const __attribute__((address_space(1))) unsigned int*)g,
        (__attribute__((address_space(3))) unsigned int*)l, 16, 0, 0);
}

// ---------------- kernel 0: forward permutation fwd[cinv[n]] = n ----------------
__global__ void fwd_perm_kernel(const int* __restrict__ cinv, int* __restrict__ fwd) {
    int n = blockIdx.x * blockDim.x + threadIdx.x;
    if (n < OUT_F) fwd[cinv[n]] = n;
}

// ---------------- kernel 1: x f32 -> bf16 (nt loads: x is read-once) ----------------
__global__ void cvt_x_kernel(const float* __restrict__ x, short* __restrict__ xb) {
    const int nv = (M_TOT * IN_F) / 8;
    for (int i = blockIdx.x * blockDim.x + threadIdx.x; i < nv;
         i += gridDim.x * blockDim.x) {
        const f32x4v* p = (const f32x4v*)(x + (long)i * 8);
        f32x4v a = __builtin_nontemporal_load(p);
        f32x4v b = __builtin_nontemporal_load(p + 1);
        bf16x8 o;
        o[0] = f2bf(a[0]); o[1] = f2bf(a[1]); o[2] = f2bf(a[2]); o[3] = f2bf(a[3]);
        o[4] = f2bf(b[0]); o[5] = f2bf(b[1]); o[6] = f2bf(b[2]); o[7] = f2bf(b[3]);
        *(bf16x8*)(xb + (long)i * 8) = o;   // xb re-read by GEMM: keep cached
    }
}

// ---------------- kernel 2: dequant (source-major) + scatter-permute ----------------
// nt loads for hw/lw (180 MB read-once codes): don't evict xb/wt from L3.
__global__ void dequant_kernel(const int* __restrict__ hw, const float* __restrict__ hs,
                               const int* __restrict__ lw, const float* __restrict__ s1,
                               const float* __restrict__ s2, const float* __restrict__ zp,
                               const int* __restrict__ fwd,
                               short* __restrict__ wt) {
    __shared__ short tile[64 * 66];
    const int t  = threadIdx.x;
    const int c0 = blockIdx.x * 64;
    const int k0 = blockIdx.y * 64;
    const int cl = t & 63;
    const int w  = t >> 6;

    if (c0 < NHIGH) {
        const int ci = c0 + cl;
        #pragma unroll
        for (int i = 0; i < 16; ++i) {
            const int kl = w + 4 * i;
            const int k  = k0 + kl;
            int   q   = __builtin_nontemporal_load(&hw[(long)k * NHIGH + ci]);
            float val = (float)q * hs[(k >> 7) * NHIGH + ci];
            tile[cl * 66 + kl] = f2bf(val);
        }
    } else {
        const int ci = c0 - NHIGH + cl;
        const float s2v = s2[ci];
        #pragma unroll
        for (int i = 0; i < 16; ++i) {
            const int kl = w + 4 * i;
            const int k  = k0 + kl;
            int   q   = __builtin_nontemporal_load(&lw[(long)k * NLOW + ci]);
            float val = ((float)q - zp[k]) * s1[k] * s2v;
            tile[cl * 66 + kl] = f2bf(val);
        }
    }
    __syncthreads();
    const int oc = t >> 2;
    const int kq = (t & 3) * 16;
    bf16x8 o0, o1;
    #pragma unroll
    for (int j = 0; j < 8; ++j) {
        o0[j] = tile[oc * 66 + kq + j];
        o1[j] = tile[oc * 66 + kq + 8 + j];
    }
    const int ndst = fwd[c0 + oc];
    short* dst = wt + (long)ndst * IN_F + k0 + kq;
    *(bf16x8*)dst       = o0;   // wt re-read by GEMM: keep cached
    *(bf16x8*)(dst + 8) = o1;
}

// ---------------- kernel 3: 256x256 8-phase GEMM ----------------
#define BM 256
#define BN 256
#define BK 64
#define KT (IN_F / BK)        // 64
#define NTIL (OUT_F / BN)     // 43
#define MTIL (M_TOT / BM)     // 16
#define NWG2 (NTIL * MTIL)    // 688 (= 8 * 86)

#define BAR()    __builtin_amdgcn_s_barrier()
#define LGKM0()  asm volatile("s_waitcnt lgkmcnt(0)" ::: "memory")
#define VMC(N)   asm volatile("s_waitcnt vmcnt(" #N ")" ::: "memory")

__global__ __launch_bounds__(512, 2) void gemm_kernel(
    const short* __restrict__ A,    // [M_TOT][IN_F] bf16
    const short* __restrict__ Bt,   // [OUT_F][IN_F] bf16
    const float* __restrict__ bias,
    float* __restrict__ C) {
    __shared__ __align__(16) short lds_s[65536];   // 128 KiB
    char* const lds = (char*)lds_s;

    const int t    = threadIdx.x;
    const int lane = t & 63;
    const int w    = t >> 6;      // 0..7
    const int wr   = w >> 2;      // 0..1  (M)
    const int wc   = w & 3;       // 0..3  (N)

    // XCD-bijective swizzle + n-outer raster: concurrent blocks per XCD span
    // ~2 B panels (4 MB, L2-resident) x 16 m-tiles (A from L3).
    const int swz = (blockIdx.x % 8) * (NWG2 / 8) + blockIdx.x / 8;
    const int nb  = swz / MTIL;
    const int mb  = swz % MTIL;
    const int m0  = mb * BM;
    const int n0  = nb * BN;

    // staging: per wave w, lane l -> half row w*8 + (l>>3),
    // source col-byte pre-swizzled: ((l&7)^(l>>3))*16
    const int srow = w * 8 + (lane >> 3);
    const int scb  = ((lane & 7) ^ (lane >> 3)) * 16;
    const char* gA0 = (const char*)A  + (long)(m0 + srow) * (IN_F * 2) + scb;
    const char* gB0 = (const char*)Bt + (long)(n0 + srow) * (IN_F * 2) + scb;

    // ds_read lane bases
    const int rl  = (lane & 15) * 128;
    const int kb0 = ((lane >> 4) * 16) ^ ((lane & 7) << 4);
    const int kb1 = kb0 ^ 64;

#define STAGE(gbase, region_off, h, ktile) do {                                  \
        const char* _g = (gbase) + (long)((h) * 128) * (IN_F * 2) + (ktile) * 128; \
        char* _l = lds + (region_off) + (h) * 16384 + w * 1024;                  \
        async16(_g,                      _l);                                    \
        async16(_g + (long)64 * (IN_F * 2), _l + 8192);                          \
    } while (0)

    f32x4 acc[8][4];
    #pragma unroll
    for (int i = 0; i < 8; ++i)
        #pragma unroll
        for (int j = 0; j < 4; ++j)
            acc[i][j] = (f32x4){0.f, 0.f, 0.f, 0.f};

    bf16x8 a[4][2], b0[2][2], b1[2][2];

#define RD_A(buf, mq) do {                                                       \
        char* _p = lds + (buf) * 65536 + wr * 16384 + (mq) * 8192 + rl;          \
        _Pragma("unroll")                                                        \
        for (int _j = 0; _j < 4; ++_j) {                                         \
            a[_j][0] = *(const bf16x8*)(_p + _j * 2048 + kb0);                   \
            a[_j][1] = *(const bf16x8*)(_p + _j * 2048 + kb1);                   \
        }                                                                        \
    } while (0)

#define RD_B(buf, nq, breg) do {                                                 \
        char* _p = lds + (buf) * 65536 + 32768 + wc * 8192 + (nq) * 4096 + rl;   \
        _Pragma("unroll")                                                        \
        for (int _n = 0; _n < 2; ++_n) {                                         \
            breg[_n][0] = *(const bf16x8*)(_p + _n * 2048 + kb0);                \
            breg[_n][1] = *(const bf16x8*)(_p + _n * 2048 + kb1);                \
        }                                                                        \
    } while (0)

#define MMA_Q(mq, nq, breg) do {                                                 \
        __builtin_amdgcn_s_setprio(1);                                           \
        _Pragma("unroll")                                                        \
        for (int _j = 0; _j < 4; ++_j)                                           \
        _Pragma("unroll")                                                        \
        for (int _n = 0; _n < 2; ++_n) {                                         \
            acc[(mq)*4+_j][(nq)*2+_n] = __builtin_amdgcn_mfma_f32_16x16x32_bf16( \
                a[_j][0], breg[_n][0], acc[(mq)*4+_j][(nq)*2+_n], 0, 0, 0);      \
            acc[(mq)*4+_j][(nq)*2+_n] = __builtin_amdgcn_mfma_f32_16x16x32_bf16( \
                a[_j][1], breg[_n][1], acc[(mq)*4+_j][(nq)*2+_n], 0, 0, 0);      \
        }                                                                        \
        __builtin_amdgcn_s_setprio(0);                                           \
    } while (0)

    // prologue: buf0 = tile 0 (4 halves), buf1.A h0 = tile 1
    STAGE(gA0, 0,     0, 0);
    STAGE(gA0, 0,     1, 0);
    STAGE(gB0, 32768, 0, 0);
    STAGE(gB0, 32768, 1, 0);
    STAGE(gA0, 65536, 0, 1);
    VMC(2);
    BAR();

    #pragma unroll 1
    for (int it = 0; it < KT / 2; ++it) {
        const int kt1 = 2 * it + 1;
        const int kt2 = (2 * it + 2 < KT) ? 2 * it + 2 : KT - 1;
        const int kt3 = (2 * it + 3 < KT) ? 2 * it + 3 : KT - 1;

        // ---- K-tile 2it (buf0) ----
        RD_A(0, 0); RD_B(0, 0, b0);
        STAGE(gA0, 65536 + 0,     1, kt1);
        BAR(); LGKM0();
        MMA_Q(0, 0, b0);
        BAR();

        RD_B(0, 1, b1);
        STAGE(gB0, 65536 + 32768, 0, kt1);
        BAR(); LGKM0();
        MMA_Q(0, 1, b1);
        BAR();

        RD_A(0, 1);
        STAGE(gB0, 65536 + 32768, 1, kt1);
        BAR(); LGKM0();
        MMA_Q(1, 1, b1);
        BAR();

        STAGE(gA0, 0,             0, kt2);
        BAR();
        MMA_Q(1, 0, b0);
        VMC(2);
        BAR();

        // ---- K-tile 2it+1 (buf1) ----
        RD_A(1, 0); RD_B(1, 0, b0);
        STAGE(gA0, 0,             1, kt2);
        BAR(); LGKM0();
        MMA_Q(0, 0, b0);
        BAR();

        RD_B(1, 1, b1);
        STAGE(gB0, 32768,         0, kt2);
        BAR(); LGKM0();
        MMA_Q(0, 1, b1);
        BAR();

        RD_A(1, 1);
        STAGE(gB0, 32768,         1, kt2);
        BAR(); LGKM0();
        MMA_Q(1, 1, b1);
        BAR();

        STAGE(gA0, 65536,         0, kt3);
        BAR();
        MMA_Q(1, 0, b0);
        VMC(2);
        BAR();
    }

    asm volatile("s_waitcnt vmcnt(0)" ::: "memory");

    // epilogue: nontemporal stores — C is write-once, never re-read; keep L3 for A/B
    const int er = m0 + wr * 128 + (lane >> 4) * 4;
    const int ec = n0 + wc * 64 + (lane & 15);
    #pragma unroll
    for (int ni = 0; ni < 4; ++ni) {
        const float bv = bias[ec + ni * 16];
        #pragma unroll
        for (int mi = 0; mi < 8; ++mi) {
            #pragma unroll
            for (int r = 0; r < 4; ++r) {
                __builtin_nontemporal_store(
                    acc[mi][ni][r] + bv,
                    &C[(long)(er + mi * 16 + r) * OUT_F + ec + ni * 16]);
            }
        }
    }
}

extern "C" void kernel_launch(void* const* d_in, const int* in_sizes, int n_in,
                              void* d_out, int out_size, void* d_ws, size_t ws_size,
                              hipStream_t stream) {
    const float* x    = (const float*)d_in[0];
    const int*   hw   = (const int*)d_in[1];
    const float* hs   = (const float*)d_in[2];
    const int*   lw   = (const int*)d_in[3];
    const float* s1   = (const float*)d_in[4];
    const float* s2   = (const float*)d_in[5];
    const float* zp   = (const float*)d_in[6];
    const int*   cinv = (const int*)d_in[7];
    const float* bias = (const float*)d_in[8];
    float*       out  = (float*)d_out;

    short* wt  = (short*)d_ws;                                     // 90,177,536 B
    short* xb  = (short*)((char*)d_ws + (size_t)OUT_F * IN_F * 2); // +33,554,432 B
    int*   fwd = (int*)((char*)d_ws + (size_t)OUT_F * IN_F * 2
                                    + (size_t)M_TOT * IN_F * 2);   // +44,032 B

    fwd_perm_kernel<<<(OUT_F + 255) / 256, 256, 0, stream>>>(cinv, fwd);
    cvt_x_kernel<<<2048, 256, 0, stream>>>(x, xb);
    dequant_kernel<<<dim3(OUT_F / 64, IN_F / 64), 256, 0, stream>>>(
        hw, hs, lw, s1, s2, zp, fwd, wt);
    gemm_kernel<<<NWG2, 512, 0, stream>>>(xb, wt, bias, out);
}

// Round 6
// 400.274 us; speedup vs baseline: 2.0032x; 1.0110x over previous
//
#include <hip/hip_runtime.h>
#include <hip/hip_bf16.h>

#define IN_F   4096
#define OUT_F  11008
#define NHIGH  2752
#define NLOW   8256
#define M_TOT  4096   // B*S = 2*2048

typedef __attribute__((ext_vector_type(8))) short bf16x8;
typedef __attribute__((ext_vector_type(4))) float f32x4;
typedef __attribute__((ext_vector_type(4))) float f32x4v;

__device__ __forceinline__ short f2bf(float f) {
    union { float f; unsigned u; } v; v.f = f;
    unsigned r = (v.u + 0x7fffu + ((v.u >> 16) & 1u)) >> 16;
    return (short)(r & 0xffffu);
}

__device__ __forceinline__ void async16(const void* g, const void* l) {
    __builtin_amdgcn_global_load_lds(
        (const __attribute__((address_space(1))) unsigned int*)g,
        (__attribute__((address_space(3))) unsigned int*)l, 16, 0, 0);
}

// ---------------- kernel 0: forward permutation fwd[cinv[n]] = n ----------------
__global__ void fwd_perm_kernel(const int* __restrict__ cinv, int* __restrict__ fwd) {
    int n = blockIdx.x * blockDim.x + threadIdx.x;
    if (n < OUT_F) fwd[cinv[n]] = n;
}

// ---------------- kernel 1: x f32 -> bf16 (nt loads: read-once) ----------------
__global__ void cvt_x_kernel(const float* __restrict__ x, short* __restrict__ xb) {
    const int nv = (M_TOT * IN_F) / 8;
    for (int i = blockIdx.x * blockDim.x + threadIdx.x; i < nv;
         i += gridDim.x * blockDim.x) {
        const f32x4v* p = (const f32x4v*)(x + (long)i * 8);
        f32x4v a = __builtin_nontemporal_load(p);
        f32x4v b = __builtin_nontemporal_load(p + 1);
        bf16x8 o;
        o[0] = f2bf(a[0]); o[1] = f2bf(a[1]); o[2] = f2bf(a[2]); o[3] = f2bf(a[3]);
        o[4] = f2bf(b[0]); o[5] = f2bf(b[1]); o[6] = f2bf(b[2]); o[7] = f2bf(b[3]);
        *(bf16x8*)(xb + (long)i * 8) = o;
    }
}

// ---------------- kernel 2: dequant (source-major) + scatter-permute ----------------
__global__ void dequant_kernel(const int* __restrict__ hw, const float* __restrict__ hs,
                               const int* __restrict__ lw, const float* __restrict__ s1,
                               const float* __restrict__ s2, const float* __restrict__ zp,
                               const int* __restrict__ fwd,
                               short* __restrict__ wt) {
    __shared__ short tile[64 * 66];
    const int t  = threadIdx.x;
    const int c0 = blockIdx.x * 64;
    const int k0 = blockIdx.y * 64;
    const int cl = t & 63;
    const int w  = t >> 6;

    if (c0 < NHIGH) {
        const int ci = c0 + cl;
        #pragma unroll
        for (int i = 0; i < 16; ++i) {
            const int kl = w + 4 * i;
            const int k  = k0 + kl;
            int   q   = __builtin_nontemporal_load(&hw[(long)k * NHIGH + ci]);
            float val = (float)q * hs[(k >> 7) * NHIGH + ci];
            tile[cl * 66 + kl] = f2bf(val);
        }
    } else {
        const int ci = c0 - NHIGH + cl;
        const float s2v = s2[ci];
        #pragma unroll
        for (int i = 0; i < 16; ++i) {
            const int kl = w + 4 * i;
            const int k  = k0 + kl;
            int   q   = __builtin_nontemporal_load(&lw[(long)k * NLOW + ci]);
            float val = ((float)q - zp[k]) * s1[k] * s2v;
            tile[cl * 66 + kl] = f2bf(val);
        }
    }
    __syncthreads();
    const int oc = t >> 2;
    const int kq = (t & 3) * 16;
    bf16x8 o0, o1;
    #pragma unroll
    for (int j = 0; j < 8; ++j) {
        o0[j] = tile[oc * 66 + kq + j];
        o1[j] = tile[oc * 66 + kq + 8 + j];
    }
    const int ndst = fwd[c0 + oc];
    short* dst = wt + (long)ndst * IN_F + k0 + kq;
    *(bf16x8*)dst       = o0;
    *(bf16x8*)(dst + 8) = o1;
}

// ---------------- kernel 3: 256x256 8-phase GEMM, quadrant-ordered ----------------
// Waves: wr in {0,1} -> 64 A-rows WITHIN a 128-row half; wc in {0..3} -> 32 B-rows
// within a half. Phase -> quadrant: ph1 (0,0), ph2 (0,1), ph3 (1,1), ph4 (1,0).
// Half read-phases: Ah0@1, Bh0@1(+regs@4), Bh1@2, Ah1@3 -> halves free mid-tile.
// Stage duties (tile U): ph1 Bh1(U+1), ph2 Ah1(U+1), ph3 Ah0(U+2), ph4 Bh0(U+2).
// Gates: VMC(8) at end of ph1, ph2, ph4 -> every load has >=4-phase lead.
#define BM 256
#define BN 256
#define BK 64
#define KT (IN_F / BK)        // 64
#define NTIL (OUT_F / BN)     // 43
#define MTIL (M_TOT / BM)     // 16
#define NWG2 (NTIL * MTIL)    // 688 (= 8 * 86)

#define BAR()    __builtin_amdgcn_s_barrier()
#define LGKM0()  asm volatile("s_waitcnt lgkmcnt(0)" ::: "memory")
#define VMC(N)   asm volatile("s_waitcnt vmcnt(" #N ")" ::: "memory")

__global__ __launch_bounds__(512, 2) void gemm_kernel(
    const short* __restrict__ A,    // [M_TOT][IN_F] bf16
    const short* __restrict__ Bt,   // [OUT_F][IN_F] bf16
    const float* __restrict__ bias,
    float* __restrict__ C) {
    __shared__ __align__(16) short lds_s[65536];   // 128 KiB
    char* const lds = (char*)lds_s;

    const int t    = threadIdx.x;
    const int lane = t & 63;
    const int w    = t >> 6;      // 0..7
    const int wr   = w >> 2;      // 0..1  (A 64-row slice within half)
    const int wc   = w & 3;       // 0..3  (B 32-row slice within half)

    // R4's proven raster: XCD-bijective swizzle + supertile (4 m-tiles/super-row)
    const int swz   = (blockIdx.x % 8) * (NWG2 / 8) + blockIdx.x / 8;
    const int sr    = swz / (4 * NTIL);
    const int in_sr = swz % (4 * NTIL);
    const int nb    = in_sr / 4;
    const int mb    = sr * 4 + (in_sr & 3);
    const int m0    = mb * BM;
    const int n0    = nb * BN;

    // staging: wave w, lane l -> half-row w*8 + (l>>3); source col-byte
    // pre-swizzled ((l&7)^(l>>3))*16
    const int srow = w * 8 + (lane >> 3);
    const int scb  = ((lane & 7) ^ (lane >> 3)) * 16;
    const char* gA0 = (const char*)A  + (long)(m0 + srow) * (IN_F * 2) + scb;
    const char* gB0 = (const char*)Bt + (long)(n0 + srow) * (IN_F * 2) + scb;

    // ds_read lane bases
    const int rl  = (lane & 15) * 128;
    const int kb0 = ((lane >> 4) * 16) ^ ((lane & 7) << 4);
    const int kb1 = kb0 ^ 64;

// stage one 128-row half of A (region_base=buf*65536) or B (+32768), half h,
// from K-tile ktile. 2 loads/thread.
#define STAGE(gbase, region_off, h, ktile) do {                                  \
        const char* _g = (gbase) + (long)((h) * 128) * (IN_F * 2) + (ktile) * 128; \
        char* _l = lds + (region_off) + (h) * 16384 + w * 1024;                  \
        async16(_g,                        _l);                                  \
        async16(_g + (long)64 * (IN_F * 2), _l + 8192);                          \
    } while (0)

    f32x4 acc[8][4];
    #pragma unroll
    for (int i = 0; i < 8; ++i)
        #pragma unroll
        for (int j = 0; j < 4; ++j)
            acc[i][j] = (f32x4){0.f, 0.f, 0.f, 0.f};

    bf16x8 a[4][2], b0[2][2], b1[2][2];

// A frag rows: half qm, row wr*64 + j*16 + (lane&15)
#define RD_A(buf, qm) do {                                                       \
        char* _p = lds + (buf) * 65536 + (qm) * 16384 + wr * 8192 + rl;          \
        _Pragma("unroll")                                                        \
        for (int _j = 0; _j < 4; ++_j) {                                         \
            a[_j][0] = *(const bf16x8*)(_p + _j * 2048 + kb0);                   \
            a[_j][1] = *(const bf16x8*)(_p + _j * 2048 + kb1);                   \
        }                                                                        \
    } while (0)

// B frag rows: half qn, row wc*32 + n*16 + (lane&15)
#define RD_B(buf, qn, breg) do {                                                 \
        char* _p = lds + (buf) * 65536 + 32768 + (qn) * 16384 + wc * 4096 + rl;  \
        _Pragma("unroll")                                                        \
        for (int _n = 0; _n < 2; ++_n) {                                         \
            breg[_n][0] = *(const bf16x8*)(_p + _n * 2048 + kb0);                \
            breg[_n][1] = *(const bf16x8*)(_p + _n * 2048 + kb1);                \
        }                                                                        \
    } while (0)

#define MMA_Q(qm, qn, breg) do {                                                 \
        __builtin_amdgcn_s_setprio(1);                                           \
        _Pragma("unroll")                                                        \
        for (int _j = 0; _j < 4; ++_j)                                           \
        _Pragma("unroll")                                                        \
        for (int _n = 0; _n < 2; ++_n) {                                         \
            acc[(qm)*4+_j][(qn)*2+_n] = __builtin_amdgcn_mfma_f32_16x16x32_bf16( \
                a[_j][0], breg[_n][0], acc[(qm)*4+_j][(qn)*2+_n], 0, 0, 0);      \
            acc[(qm)*4+_j][(qn)*2+_n] = __builtin_amdgcn_mfma_f32_16x16x32_bf16( \
                a[_j][1], breg[_n][1], acc[(qm)*4+_j][(qn)*2+_n], 0, 0, 0);      \
        }                                                                        \
        __builtin_amdgcn_s_setprio(0);                                           \
    } while (0)

    // prologue (steady-state issue order): tile0 all 4 halves + Ah0(1), Bh0(1)
    STAGE(gA0, 0,             0, 0);   // A h0(0)
    STAGE(gB0, 32768,         0, 0);   // B h0(0)
    STAGE(gB0, 32768,         1, 0);   // B h1(0)
    STAGE(gA0, 0,             1, 0);   // A h1(0)
    STAGE(gA0, 65536,         0, 1);   // A h0(1)
    STAGE(gB0, 65536 + 32768, 0, 1);   // B h0(1)
    VMC(8);                            // tile0's 4 halves landed
    BAR();

    #pragma unroll 1
    for (int it = 0; it < KT / 2; ++it) {
        const int kt1 = 2 * it + 1;                               // always < KT
        const int c2  = (2 * it + 2 < KT) ? 2 * it + 2 : KT - 1;  // clamp: benign restage
        const int c3  = (2 * it + 3 < KT) ? 2 * it + 3 : KT - 1;
        const int r2  = (c2 & 1) * 65536;
        const int r3  = (c3 & 1) * 65536;

        // ======== even tile E=2it (buf0) ========
        // ph1: quadrant (0,0)
        RD_A(0, 0); RD_B(0, 0, b0);
        STAGE(gB0, 65536 + 32768, 1, kt1);        // B h1(E+1)
        BAR(); LGKM0();
        MMA_Q(0, 0, b0);
        VMC(8); BAR();                            // gate: B h1(E) landed
        // ph2: quadrant (0,1)
        RD_B(0, 1, b1);
        STAGE(gA0, 65536,         1, kt1);        // A h1(E+1)
        BAR(); LGKM0();
        MMA_Q(0, 1, b1);
        VMC(8); BAR();                            // gate: A h1(E) landed
        // ph3: quadrant (1,1)
        RD_A(0, 1);
        STAGE(gA0, r2,            0, c2);         // A h0(E+2)
        BAR(); LGKM0();
        MMA_Q(1, 1, b1);
        BAR();
        // ph4: quadrant (1,0)  (a from ph3, b0 from ph1 - regs)
        STAGE(gB0, r2 + 32768,    0, c2);         // B h0(E+2)
        BAR();
        MMA_Q(1, 0, b0);
        VMC(8); BAR();                            // gate: A h0(E+1), B h0(E+1) landed

        // ======== odd tile O=2it+1 (buf1) ========
        // ph1
        RD_A(1, 0); RD_B(1, 0, b0);
        STAGE(gB0, r2 + 32768,    1, c2);         // B h1(O+1)
        BAR(); LGKM0();
        MMA_Q(0, 0, b0);
        VMC(8); BAR();
        // ph2
        RD_B(1, 1, b1);
        STAGE(gA0, r2,            1, c2);         // A h1(O+1)
        BAR(); LGKM0();
        MMA_Q(0, 1, b1);
        VMC(8); BAR();
        // ph3
        RD_A(1, 1);
        STAGE(gA0, r3,            0, c3);         // A h0(O+2)
        BAR(); LGKM0();
        MMA_Q(1, 1, b1);
        BAR();
        // ph4
        STAGE(gB0, r3 + 32768,    0, c3);         // B h0(O+2)
        BAR();
        MMA_Q(1, 0, b0);
        VMC(8); BAR();
    }

    asm volatile("s_waitcnt vmcnt(0)" ::: "memory");

    // epilogue: nt stores. row = m0+(mi>>2)*128+wr*64+(mi&3)*16+(lane>>4)*4+r
    //           col = n0+(ni>>1)*128+wc*32+(ni&1)*16+(lane&15)
    #pragma unroll
    for (int ni = 0; ni < 4; ++ni) {
        const int ec = n0 + (ni >> 1) * 128 + wc * 32 + (ni & 1) * 16 + (lane & 15);
        const float bv = bias[ec];
        #pragma unroll
        for (int mi = 0; mi < 8; ++mi) {
            const int er = m0 + (mi >> 2) * 128 + wr * 64 + (mi & 3) * 16 + (lane >> 4) * 4;
            #pragma unroll
            for (int r = 0; r < 4; ++r) {
                __builtin_nontemporal_store(acc[mi][ni][r] + bv,
                                            &C[(long)(er + r) * OUT_F + ec]);
            }
        }
    }
}

extern "C" void kernel_launch(void* const* d_in, const int* in_sizes, int n_in,
                              void* d_out, int out_size, void* d_ws, size_t ws_size,
                              hipStream_t stream) {
    const float* x    = (const float*)d_in[0];
    const int*   hw   = (const int*)d_in[1];
    const float* hs   = (const float*)d_in[2];
    const int*   lw   = (const int*)d_in[3];
    const float* s1   = (const float*)d_in[4];
    const float* s2   = (const float*)d_in[5];
    const float* zp   = (const float*)d_in[6];
    const int*   cinv = (const int*)d_in[7];
    const float* bias = (const float*)d_in[8];
    float*       out  = (float*)d_out;

    short* wt  = (short*)d_ws;                                     // 90,177,536 B
    short* xb  = (short*)((char*)d_ws + (size_t)OUT_F * IN_F * 2); // +33,554,432 B
    int*   fwd = (int*)((char*)d_ws + (size_t)OUT_F * IN_F * 2
                                    + (size_t)M_TOT * IN_F * 2);   // +44,032 B

    fwd_perm_kernel<<<(OUT_F + 255) / 256, 256, 0, stream>>>(cinv, fwd);
    cvt_x_kernel<<<2048, 256, 0, stream>>>(x, xb);
    dequant_kernel<<<dim3(OUT_F / 64, IN_F / 64), 256, 0, stream>>>(
        hw, hs, lw, s1, s2, zp, fwd, wt);
    gemm_kernel<<<NWG2, 512, 0, stream>>>(xb, wt, bias, out);
}